// Round 18
// baseline (77.366 us; speedup 1.0000x reference)
//
#include <hip/hip_runtime.h>
#include <hip/hip_bf16.h>
#include <stdint.h>

// y[p, j] = sum_i Alpha[p, i] * (X_ref[i] . X_in[j])^expK * [Z_ref[i] == Z[j]]
// Grouped formulation (4 element groups). Round-18 = round-17 (69.2us) with:
// (1) ALL s_setprio removed — m190: setprio is NEGATIVE on lockstep
//     barrier-synced GEMM structures (only pays with phase-role diversity);
// (2) aP (Alpha) loads hoisted to tile START — previously issued after the
//     next-tile stage loads, so the compiler's aP-wait retired the entire
//     depth-2 prefetch at every tile boundary. Hoisting keeps the pipeline
//     continuous; in-loop vmcnt(8) retires aP by phase 2 (L2-hot, cheap).
// Everything else identical to r17 (bf16 partials, 3-buffer 48KB, nsplit=12).

typedef __attribute__((ext_vector_type(8))) short bf16x8;
typedef __attribute__((ext_vector_type(4))) float f32x4;
typedef __attribute__((ext_vector_type(4))) unsigned int u32x4;

#define DFEAT  384
#define NREF   8192
#define NIN    8192
#define NPROPS 64
#define BJ 128
#define BI 128
#define BK 32
#define KSTEPS (DFEAT / BK)        // 12
#define CAP    8704                // 8192 + 4*128 (worst-case padded slots)
#define NSTRIP (CAP / BJ)          // 68

__device__ __forceinline__ void gload_lds16(const void* g, void* l) {
  __builtin_amdgcn_global_load_lds(
      (const __attribute__((address_space(1))) void*)g,
      (__attribute__((address_space(3))) void*)l,
      16, 0, 0);
}

__device__ __forceinline__ unsigned short bfbits(float f) {
  __hip_bfloat16 h = __float2bfloat16(f);
  return __builtin_bit_cast(unsigned short, h);
}

__device__ __forceinline__ float bf2f(unsigned short u) {
  return __builtin_bit_cast(float, (uint32_t)u << 16);
}

__device__ __forceinline__ float pwr(float s, int expK) {
  if (expK == 2) return s * s;
  float r = 1.0f;
  for (int e = 0; e < expK; ++e) r *= s;
  return r;
}

// ---- stable partition of both label arrays (2 blocks, one each) ----
__global__ __launch_bounds__(256) void partition2_kernel(
    const int* __restrict__ Za, const int* __restrict__ Zb,
    int* __restrict__ perma, int* __restrict__ permb,
    int* __restrict__ goffa, int* __restrict__ goffb) {
  const int* Zin = blockIdx.x ? Zb : Za;
  int* perm = blockIdx.x ? permb : perma;
  int* goff = blockIdx.x ? goffb : goffa;

  __shared__ int cnt[256][4];
  __shared__ int gstart[4];
  __shared__ int gtot[4];
  const int t = threadIdx.x;
  const int base = t * 32;           // 8192 / 256

  int c[4] = {0, 0, 0, 0};
  int zloc[32];
  #pragma unroll
  for (int e = 0; e < 32; ++e) {
    zloc[e] = (Zin[base + e] - 1) & 3;   // labels are 1..4
    ++c[zloc[e]];
  }
  #pragma unroll
  for (int b = 0; b < 4; ++b) cnt[t][b] = c[b];
  __syncthreads();

  const int w = t >> 6, l = t & 63;
  {
    int v0 = cnt[4 * l + 0][w], v1 = cnt[4 * l + 1][w];
    int v2 = cnt[4 * l + 2][w], v3 = cnt[4 * l + 3][w];
    int s = v0 + v1 + v2 + v3;
    int inc = s;
    #pragma unroll
    for (int d = 1; d < 64; d <<= 1) {
      int o = __shfl_up(inc, d, 64);
      if (l >= d) inc += o;
    }
    const int excl = inc - s;
    cnt[4 * l + 0][w] = excl;
    cnt[4 * l + 1][w] = excl + v0;
    cnt[4 * l + 2][w] = excl + v0 + v1;
    cnt[4 * l + 3][w] = excl + v0 + v1 + v2;
    if (l == 63) gtot[w] = inc;
  }
  __syncthreads();

  if (t == 0) {
    int off = 0;
    #pragma unroll
    for (int b = 0; b < 4; ++b) {
      gstart[b] = off; goff[b] = off;
      off += ((gtot[b] + 127) >> 7) << 7;   // pad to 128
    }
    goff[4] = off;
  }
  __syncthreads();

  for (int s = t; s < CAP; s += 256) perm[s] = -1;
  __syncthreads();

  int pos[4];
  #pragma unroll
  for (int b = 0; b < 4; ++b) pos[b] = gstart[b] + cnt[t][b];
  #pragma unroll
  for (int e = 0; e < 32; ++e) {
    const int z = zloc[e];
    perm[pos[z]++] = base + e;
  }
}

// ---- merged gather: Xr (perm_i), Xi (perm_j), Alpha (perm_i, permuted) ----
#define XSEC (CAP * (DFEAT / 4) / 256)     // 3264 blocks per X section
__global__ void gather_all(const float* __restrict__ Xr_in,
                           const float* __restrict__ Xi_in,
                           const float* __restrict__ Al_in,
                           const int* __restrict__ perm_i,
                           const int* __restrict__ perm_j,
                           __hip_bfloat16* __restrict__ Xr_g,
                           __hip_bfloat16* __restrict__ Xi_g,
                           __hip_bfloat16* __restrict__ Ab_g) {
  const int b = blockIdx.x;
  if (b < 2 * XSEC) {
    const bool isA = (b < XSEC);
    const float* in = isA ? Xr_in : Xi_in;
    const int* perm = isA ? perm_i : perm_j;
    __hip_bfloat16* out = isA ? Xr_g : Xi_g;
    const int idx = (isA ? b : b - XSEC) * 256 + threadIdx.x;
    const int per_row = DFEAT / 4;
    const int slot = idx / per_row;
    const int c4 = (idx % per_row) * 4;
    const int src = perm[slot];
    ushort4 o = make_ushort4(0, 0, 0, 0);
    if (src >= 0) {
      float4 v = *reinterpret_cast<const float4*>(in + (size_t)src * DFEAT + c4);
      o.x = bfbits(v.x); o.y = bfbits(v.y); o.z = bfbits(v.z); o.w = bfbits(v.w);
    }
    *reinterpret_cast<ushort4*>(out + (size_t)slot * DFEAT + c4) = o;
  } else {
    // Ab_g[p][32b + l4*8 + eh*4 + r] = Alpha[p][perm_i[32b + eh*16 + l4*4 + r]]
    const int t = (b - 2 * XSEC) * 256 + threadIdx.x;   // NPROPS * CAP/4
    const int per_row = CAP / 4;
    const int p  = t / per_row;
    const int c4 = t % per_row;
    const int blk = c4 >> 3;
    const int g   = c4 & 7;
    const int l4g = g >> 1;
    const int eh  = g & 1;
    ushort4 o;
    unsigned short* op = &o.x;
    #pragma unroll
    for (int r = 0; r < 4; ++r) {
      const int slot = blk * 32 + eh * 16 + l4g * 4 + r;
      const int src = perm_i[slot];
      op[r] = (src >= 0) ? bfbits(Al_in[(size_t)p * NREF + src]) : (unsigned short)0;
    }
    *reinterpret_cast<ushort4*>(Ab_g + (size_t)p * CAP + blk * 32 + l4g * 8 + eh * 4) = o;
  }
}

// sum nsplit bf16 partials and scatter slot -> original column
__global__ void reduce_scatter(const unsigned short* __restrict__ partial,
                               const int* __restrict__ permj,
                               float* __restrict__ out, int nsplit) {
  const int idx = blockIdx.x * blockDim.x + threadIdx.x;  // NPROPS * CAP / 4
  const int per_row = CAP / 4;
  const int p = idx / per_row;
  const int s4 = (idx % per_row) * 4;
  float4 s = make_float4(0.f, 0.f, 0.f, 0.f);
  for (int sp = 0; sp < nsplit; ++sp) {
    const ushort4 v = *reinterpret_cast<const ushort4*>(
        partial + (size_t)sp * NPROPS * CAP + (size_t)p * CAP + s4);
    s.x += bf2f(v.x); s.y += bf2f(v.y); s.z += bf2f(v.z); s.w += bf2f(v.w);
  }
  const int4 dst = *reinterpret_cast<const int4*>(permj + s4);
  float* po = out + (size_t)p * NIN;
  if (dst.x >= 0) po[dst.x] = s.x;
  if (dst.y >= 0) po[dst.y] = s.y;
  if (dst.z >= 0) po[dst.z] = s.z;
  if (dst.w >= 0) po[dst.w] = s.w;
}

__global__ __launch_bounds__(256, 2) void fused_poly_kernel(
    const __hip_bfloat16* __restrict__ Xr,   // [CAP][DFEAT] gathered ref rows
    const __hip_bfloat16* __restrict__ Xi,   // [CAP][DFEAT] gathered query rows
    const __hip_bfloat16* __restrict__ Abp,  // [NPROPS][CAP] gathered+permuted
    const int* __restrict__ ioff,            // [5] padded i-group offsets
    const int* __restrict__ joff,            // [5] padded j-group offsets
    const int* __restrict__ expKp,
    unsigned short* __restrict__ partial,    // [nsplit][NPROPS][CAP] bf16
    int nsplit, int chunk)                   // chunk = gridDim.x / 8
{
  // XCD-chunked bijective swizzle (round-6 proved FETCH 45->17MB)
  const int flat = blockIdx.x;
  const int newflat = (flat & 7) * chunk + (flat >> 3);
  const int strip = newflat / nsplit;
  const int split = newflat % nsplit;
  const int j0 = strip * BJ;
  if (j0 >= joff[4]) return;                 // dead strip

  int grp = 0;
  grp += (j0 >= joff[1]);
  grp += (j0 >= joff[2]);
  grp += (j0 >= joff[3]);
  const int ibase = ioff[grp];
  const int ntiles_g = (ioff[grp + 1] - ibase) / BI;
  const int tb = ntiles_g / nsplit;
  const int rem = ntiles_g % nsplit;
  const int ntiles = tb + (split < rem ? 1 : 0);
  const int tile_begin = split * tb + (split < rem ? split : rem);

  const int tid  = threadIdx.x;
  const int wid  = tid >> 6;      // 4 waves
  const int lane = tid & 63;
  const int l15  = lane & 15;
  const int l4   = lane >> 4;
  const int wi   = wid >> 1;      // wave row over i (2)
  const int wj   = wid & 1;       // wave col over j (2)

  // LDS 48KB: 3 buffers x (A 8KB + B 8KB) -> 3 blocks/CU (144KB of 160KB)
  __shared__ char smem[49152];

  const int expK = *expKp;

  // read-side swizzle: slot = l4 ^ ((row>>1)&3); row = *+l15 -> ((l15>>1)&3)
  const int rsl = (l4 ^ ((l15 >> 1) & 3)) << 4;   // byte offset within row
  // stage-side: linear LDS dest; source col pre-swizzled (involution)
  const int scol = ((lane & 3) ^ ((lane >> 3) & 3)) * 8;   // bf16 column
  const int srow = lane >> 2;                               // row in 16-chunk

  // per stage per wave: 4 gload_lds (2 A-chunks + 2 B-chunks of 1KB)
  auto stage = [&](int buf, int i0s, int kks) {
    char* Ab_ = smem + buf * 16384;
    char* Bb_ = smem + buf * 16384 + 8192;
    #pragma unroll
    for (int q = 0; q < 2; ++q) {
      const int grow = wid * 32 + q * 16 + srow;
      const size_t gc = (size_t)kks * BK + scol;
      gload_lds16(Xr + (size_t)(i0s + grow) * DFEAT + gc,
                  Ab_ + wid * 2048 + q * 1024);
      gload_lds16(Xi + (size_t)(j0 + grow) * DFEAT + gc,
                  Bb_ + wid * 2048 + q * 1024);
    }
  };

  f32x4 accO[4][4];                       // p 64 x (this wave's j 64)
  #pragma unroll
  for (int a = 0; a < 4; ++a)
    #pragma unroll
    for (int n = 0; n < 4; ++n)
      accO[a][n] = (f32x4){0.f, 0.f, 0.f, 0.f};

  if (ntiles > 0) {
    // ---- prologue: depth-2 prefetch, NO drain ----
    stage(0, ibase + tile_begin * BI, 0);
    stage(1, ibase + tile_begin * BI, 1);

    for (int t = 0; t < ntiles; ++t) {
      const int i0c = ibase + (tile_begin + t) * BI;
      const int i0n = i0c + BI;

      // ---- aP loads at tile START: issued before any of this tile's
      // K-loop stages beyond ph0/ph1, so the in-loop vmcnt(8)s retire them
      // by phase 2 and the tail needs NO vm-wait (cross-tile prefetch stays
      // in flight across the tile boundary).
      bf16x8 aP[2][4];
      #pragma unroll
      for (int ks = 0; ks < 2; ++ks)
        #pragma unroll
        for (int a = 0; a < 4; ++a)
          aP[ks][a] = *reinterpret_cast<const bf16x8*>(
              Abp + (size_t)(a * 16 + l15) * CAP + i0c + wi * 64 + ks * 32 + l4 * 8);

      f32x4 acc[4][4];
      #pragma unroll
      for (int m = 0; m < 4; ++m)
        #pragma unroll
        for (int n = 0; n < 4; ++n)
          acc[m][n] = (f32x4){0.f, 0.f, 0.f, 0.f};

      // ---- 12 K-steps; compute buf = ph%3, stage buf = (ph+2)%3 ----
      #pragma unroll
      for (int ph = 0; ph < KSTEPS; ++ph) {
        const int cb = ph % 3;
        const int sb = (ph + 2) % 3;
        if (ph <= 9) {
          stage(sb, i0c, ph + 2);
          asm volatile("s_waitcnt vmcnt(8)" ::: "memory");
        } else if (t + 1 < ntiles) {
          stage(sb, i0n, ph - 10);
          asm volatile("s_waitcnt vmcnt(8)" ::: "memory");
        } else if (ph == 10) {
          asm volatile("s_waitcnt vmcnt(4)" ::: "memory");
        } else {
          asm volatile("s_waitcnt vmcnt(0)" ::: "memory");
        }
        __builtin_amdgcn_s_barrier();     // all waves' step-ph loads landed

        char* Ab_ = smem + cb * 16384;
        char* Bb_ = smem + cb * 16384 + 8192;
        {
          bf16x8 aF[4], bF[4];
          #pragma unroll
          for (int m = 0; m < 4; ++m) {
            const int rA = wi * 64 + m * 16 + l15;
            aF[m] = *reinterpret_cast<const bf16x8*>(Ab_ + rA * 64 + rsl);
          }
          #pragma unroll
          for (int n = 0; n < 4; ++n) {
            const int rB = wj * 64 + n * 16 + l15;
            bF[n] = *reinterpret_cast<const bf16x8*>(Bb_ + rB * 64 + rsl);
          }
          #pragma unroll
          for (int m = 0; m < 4; ++m)
            #pragma unroll
            for (int n = 0; n < 4; ++n)
              acc[m][n] = __builtin_amdgcn_mfma_f32_16x16x32_bf16(
                  aF[m], bF[n], acc[m][n], 0, 0, 0);
        }
        asm volatile("s_waitcnt lgkmcnt(0)" ::: "memory");  // my reads done
        __builtin_amdgcn_s_barrier();     // buf cb free for overwrite
      }

      // ---- tail: square+pack, lane-local PV (aP already resident) ----
      #pragma unroll
      for (int ks = 0; ks < 2; ++ks) {
        #pragma unroll
        for (int n = 0; n < 4; ++n) {
          const f32x4 s0 = acc[2 * ks][n];
          const f32x4 s1 = acc[2 * ks + 1][n];
          u32x4 tw;
          tw[0] = (uint32_t)bfbits(pwr(s0[0], expK)) |
                  ((uint32_t)bfbits(pwr(s0[1], expK)) << 16);
          tw[1] = (uint32_t)bfbits(pwr(s0[2], expK)) |
                  ((uint32_t)bfbits(pwr(s0[3], expK)) << 16);
          tw[2] = (uint32_t)bfbits(pwr(s1[0], expK)) |
                  ((uint32_t)bfbits(pwr(s1[1], expK)) << 16);
          tw[3] = (uint32_t)bfbits(pwr(s1[2], expK)) |
                  ((uint32_t)bfbits(pwr(s1[3], expK)) << 16);
          const bf16x8 bP = __builtin_bit_cast(bf16x8, tw);
          #pragma unroll
          for (int a = 0; a < 4; ++a)
            accO[a][n] = __builtin_amdgcn_mfma_f32_16x16x32_bf16(
                aP[ks][a], bP, accO[a][n], 0, 0, 0);
        }
      }
    }
  }

  // ---- cross-wi reduce via LDS (rb 32KB fits in 48KB smem) + bf16 store ----
  __syncthreads();
  float* rb = (float*)smem;        // [wj 2][p 64][j 64] floats
  if (wi == 1) {
    #pragma unroll
    for (int a = 0; a < 4; ++a)
      #pragma unroll
      for (int n = 0; n < 4; ++n)
        #pragma unroll
        for (int r = 0; r < 4; ++r)
          rb[wj * 4096 + (a * 16 + l4 * 4 + r) * 64 + n * 16 + l15] =
              accO[a][n][r];
  }
  __syncthreads();
  if (wi == 0) {
    unsigned short* po = partial + (size_t)split * NPROPS * CAP;
    #pragma unroll
    for (int a = 0; a < 4; ++a)
      #pragma unroll
      for (int n = 0; n < 4; ++n)
        #pragma unroll
        for (int r = 0; r < 4; ++r) {
          const int p = a * 16 + l4 * 4 + r;
          const int jl = wj * 64 + n * 16 + l15;
          po[(size_t)p * CAP + j0 + jl] =
              bfbits(accO[a][n][r] + rb[wj * 4096 + p * 64 + n * 16 + l15]);
        }
  }
}

extern "C" void kernel_launch(void* const* d_in, const int* in_sizes, int n_in,
                              void* d_out, int out_size, void* d_ws, size_t ws_size,
                              hipStream_t stream) {
  (void)in_sizes; (void)n_in; (void)out_size;
  const float* Alpha = (const float*)d_in[0];
  const float* X_ref = (const float*)d_in[1];
  const float* desc  = (const float*)d_in[2];
  const int*   Z_ref = (const int*)d_in[3];
  const int*   Z     = (const int*)d_in[4];
  const int*   expK  = (const int*)d_in[5];
  float* out = (float*)d_out;

  char* ws = (char*)d_ws;
  size_t off = 0;
  auto alloc = [&](size_t b) { void* p = ws + off; off = (off + b + 255) & ~255ULL; return p; };

  int* perm_i = (int*)alloc(CAP * 4);
  int* perm_j = (int*)alloc(CAP * 4);
  int* ioff   = (int*)alloc(8 * 4);
  int* joff   = (int*)alloc(8 * 4);
  __hip_bfloat16* Xr_g = (__hip_bfloat16*)alloc((size_t)CAP * DFEAT * 2);
  __hip_bfloat16* Xi_g = (__hip_bfloat16*)alloc((size_t)CAP * DFEAT * 2);
  __hip_bfloat16* Ab_g = (__hip_bfloat16*)alloc((size_t)NPROPS * CAP * 2);

  // nsplit=12 -> grid 816 (=8x102): 3 resident blocks/CU (48KB LDS)
  int nsplit = 12;
  while (nsplit > 4 && off + (size_t)nsplit * NPROPS * CAP * 2 > ws_size) nsplit -= 4;
  unsigned short* partial =
      (unsigned short*)alloc((size_t)nsplit * NPROPS * CAP * 2);

  partition2_kernel<<<dim3(2), 256, 0, stream>>>(
      Z_ref, Z, perm_i, perm_j, ioff, joff);

  gather_all<<<dim3(2 * XSEC + NPROPS * (CAP / 4) / 256), 256, 0, stream>>>(
      X_ref, desc, Alpha, perm_i, perm_j, Xr_g, Xi_g, Ab_g);

  const int grid = NSTRIP * nsplit;          // 816, divisible by 8
  fused_poly_kernel<<<dim3(grid), 256, 0, stream>>>(
      Xr_g, Xi_g, Ab_g, ioff, joff, expK, partial, nsplit, grid / 8);

  reduce_scatter<<<dim3(NPROPS * (CAP / 4) / 256), 256, 0, stream>>>(
      partial, perm_j, out, nsplit);
}

// Round 19
// 69.137 us; speedup vs baseline: 1.1190x; 1.1190x over previous
//
#include <hip/hip_runtime.h>
#include <hip/hip_bf16.h>
#include <stdint.h>

// y[p, j] = sum_i Alpha[p, i] * (X_ref[i] . X_in[j])^expK * [Z_ref[i] == Z[j]]
// Grouped formulation (4 element groups). Round-19 = EXACT revert to round-17
// (best measured: 69.2us total, fused 40.6us). Round-18's two edits both
// reverted: aP-hoist broke the in-loop vmcnt(8) accounting (aP loads mixed
// into the stage queue -> over-wait at tile entry), and setprio removal was
// not the win m190 suggested (3 blocks/CU co-residency = role diversity).
// Config: 3-buffer 48KB LDS depth-2 counted-vmcnt pipeline, corrected XOR
// swizzle, lane-local PV tail, bf16 partials, nsplit=12, XCD-chunked swizzle.

typedef __attribute__((ext_vector_type(8))) short bf16x8;
typedef __attribute__((ext_vector_type(4))) float f32x4;
typedef __attribute__((ext_vector_type(4))) unsigned int u32x4;

#define DFEAT  384
#define NREF   8192
#define NIN    8192
#define NPROPS 64
#define BJ 128
#define BI 128
#define BK 32
#define KSTEPS (DFEAT / BK)        // 12
#define CAP    8704                // 8192 + 4*128 (worst-case padded slots)
#define NSTRIP (CAP / BJ)          // 68

__device__ __forceinline__ void gload_lds16(const void* g, void* l) {
  __builtin_amdgcn_global_load_lds(
      (const __attribute__((address_space(1))) void*)g,
      (__attribute__((address_space(3))) void*)l,
      16, 0, 0);
}

__device__ __forceinline__ unsigned short bfbits(float f) {
  __hip_bfloat16 h = __float2bfloat16(f);
  return __builtin_bit_cast(unsigned short, h);
}

__device__ __forceinline__ float bf2f(unsigned short u) {
  return __builtin_bit_cast(float, (uint32_t)u << 16);
}

__device__ __forceinline__ float pwr(float s, int expK) {
  if (expK == 2) return s * s;
  float r = 1.0f;
  for (int e = 0; e < expK; ++e) r *= s;
  return r;
}

// ---- stable partition of both label arrays (2 blocks, one each) ----
__global__ __launch_bounds__(256) void partition2_kernel(
    const int* __restrict__ Za, const int* __restrict__ Zb,
    int* __restrict__ perma, int* __restrict__ permb,
    int* __restrict__ goffa, int* __restrict__ goffb) {
  const int* Zin = blockIdx.x ? Zb : Za;
  int* perm = blockIdx.x ? permb : perma;
  int* goff = blockIdx.x ? goffb : goffa;

  __shared__ int cnt[256][4];
  __shared__ int gstart[4];
  __shared__ int gtot[4];
  const int t = threadIdx.x;
  const int base = t * 32;           // 8192 / 256

  int c[4] = {0, 0, 0, 0};
  int zloc[32];
  #pragma unroll
  for (int e = 0; e < 32; ++e) {
    zloc[e] = (Zin[base + e] - 1) & 3;   // labels are 1..4
    ++c[zloc[e]];
  }
  #pragma unroll
  for (int b = 0; b < 4; ++b) cnt[t][b] = c[b];
  __syncthreads();

  const int w = t >> 6, l = t & 63;
  {
    int v0 = cnt[4 * l + 0][w], v1 = cnt[4 * l + 1][w];
    int v2 = cnt[4 * l + 2][w], v3 = cnt[4 * l + 3][w];
    int s = v0 + v1 + v2 + v3;
    int inc = s;
    #pragma unroll
    for (int d = 1; d < 64; d <<= 1) {
      int o = __shfl_up(inc, d, 64);
      if (l >= d) inc += o;
    }
    const int excl = inc - s;
    cnt[4 * l + 0][w] = excl;
    cnt[4 * l + 1][w] = excl + v0;
    cnt[4 * l + 2][w] = excl + v0 + v1;
    cnt[4 * l + 3][w] = excl + v0 + v1 + v2;
    if (l == 63) gtot[w] = inc;
  }
  __syncthreads();

  if (t == 0) {
    int off = 0;
    #pragma unroll
    for (int b = 0; b < 4; ++b) {
      gstart[b] = off; goff[b] = off;
      off += ((gtot[b] + 127) >> 7) << 7;   // pad to 128
    }
    goff[4] = off;
  }
  __syncthreads();

  for (int s = t; s < CAP; s += 256) perm[s] = -1;
  __syncthreads();

  int pos[4];
  #pragma unroll
  for (int b = 0; b < 4; ++b) pos[b] = gstart[b] + cnt[t][b];
  #pragma unroll
  for (int e = 0; e < 32; ++e) {
    const int z = zloc[e];
    perm[pos[z]++] = base + e;
  }
}

// ---- merged gather: Xr (perm_i), Xi (perm_j), Alpha (perm_i, permuted) ----
#define XSEC (CAP * (DFEAT / 4) / 256)     // 3264 blocks per X section
__global__ void gather_all(const float* __restrict__ Xr_in,
                           const float* __restrict__ Xi_in,
                           const float* __restrict__ Al_in,
                           const int* __restrict__ perm_i,
                           const int* __restrict__ perm_j,
                           __hip_bfloat16* __restrict__ Xr_g,
                           __hip_bfloat16* __restrict__ Xi_g,
                           __hip_bfloat16* __restrict__ Ab_g) {
  const int b = blockIdx.x;
  if (b < 2 * XSEC) {
    const bool isA = (b < XSEC);
    const float* in = isA ? Xr_in : Xi_in;
    const int* perm = isA ? perm_i : perm_j;
    __hip_bfloat16* out = isA ? Xr_g : Xi_g;
    const int idx = (isA ? b : b - XSEC) * 256 + threadIdx.x;
    const int per_row = DFEAT / 4;
    const int slot = idx / per_row;
    const int c4 = (idx % per_row) * 4;
    const int src = perm[slot];
    ushort4 o = make_ushort4(0, 0, 0, 0);
    if (src >= 0) {
      float4 v = *reinterpret_cast<const float4*>(in + (size_t)src * DFEAT + c4);
      o.x = bfbits(v.x); o.y = bfbits(v.y); o.z = bfbits(v.z); o.w = bfbits(v.w);
    }
    *reinterpret_cast<ushort4*>(out + (size_t)slot * DFEAT + c4) = o;
  } else {
    // Ab_g[p][32b + l4*8 + eh*4 + r] = Alpha[p][perm_i[32b + eh*16 + l4*4 + r]]
    const int t = (b - 2 * XSEC) * 256 + threadIdx.x;   // NPROPS * CAP/4
    const int per_row = CAP / 4;
    const int p  = t / per_row;
    const int c4 = t % per_row;
    const int blk = c4 >> 3;
    const int g   = c4 & 7;
    const int l4g = g >> 1;
    const int eh  = g & 1;
    ushort4 o;
    unsigned short* op = &o.x;
    #pragma unroll
    for (int r = 0; r < 4; ++r) {
      const int slot = blk * 32 + eh * 16 + l4g * 4 + r;
      const int src = perm_i[slot];
      op[r] = (src >= 0) ? bfbits(Al_in[(size_t)p * NREF + src]) : (unsigned short)0;
    }
    *reinterpret_cast<ushort4*>(Ab_g + (size_t)p * CAP + blk * 32 + l4g * 8 + eh * 4) = o;
  }
}

// sum nsplit bf16 partials and scatter slot -> original column
__global__ void reduce_scatter(const unsigned short* __restrict__ partial,
                               const int* __restrict__ permj,
                               float* __restrict__ out, int nsplit) {
  const int idx = blockIdx.x * blockDim.x + threadIdx.x;  // NPROPS * CAP / 4
  const int per_row = CAP / 4;
  const int p = idx / per_row;
  const int s4 = (idx % per_row) * 4;
  float4 s = make_float4(0.f, 0.f, 0.f, 0.f);
  for (int sp = 0; sp < nsplit; ++sp) {
    const ushort4 v = *reinterpret_cast<const ushort4*>(
        partial + (size_t)sp * NPROPS * CAP + (size_t)p * CAP + s4);
    s.x += bf2f(v.x); s.y += bf2f(v.y); s.z += bf2f(v.z); s.w += bf2f(v.w);
  }
  const int4 dst = *reinterpret_cast<const int4*>(permj + s4);
  float* po = out + (size_t)p * NIN;
  if (dst.x >= 0) po[dst.x] = s.x;
  if (dst.y >= 0) po[dst.y] = s.y;
  if (dst.z >= 0) po[dst.z] = s.z;
  if (dst.w >= 0) po[dst.w] = s.w;
}

__global__ __launch_bounds__(256, 2) void fused_poly_kernel(
    const __hip_bfloat16* __restrict__ Xr,   // [CAP][DFEAT] gathered ref rows
    const __hip_bfloat16* __restrict__ Xi,   // [CAP][DFEAT] gathered query rows
    const __hip_bfloat16* __restrict__ Abp,  // [NPROPS][CAP] gathered+permuted
    const int* __restrict__ ioff,            // [5] padded i-group offsets
    const int* __restrict__ joff,            // [5] padded j-group offsets
    const int* __restrict__ expKp,
    unsigned short* __restrict__ partial,    // [nsplit][NPROPS][CAP] bf16
    int nsplit, int chunk)                   // chunk = gridDim.x / 8
{
  // XCD-chunked bijective swizzle (round-6 proved FETCH 45->17MB)
  const int flat = blockIdx.x;
  const int newflat = (flat & 7) * chunk + (flat >> 3);
  const int strip = newflat / nsplit;
  const int split = newflat % nsplit;
  const int j0 = strip * BJ;
  if (j0 >= joff[4]) return;                 // dead strip

  int grp = 0;
  grp += (j0 >= joff[1]);
  grp += (j0 >= joff[2]);
  grp += (j0 >= joff[3]);
  const int ibase = ioff[grp];
  const int ntiles_g = (ioff[grp + 1] - ibase) / BI;
  const int tb = ntiles_g / nsplit;
  const int rem = ntiles_g % nsplit;
  const int ntiles = tb + (split < rem ? 1 : 0);
  const int tile_begin = split * tb + (split < rem ? split : rem);

  const int tid  = threadIdx.x;
  const int wid  = tid >> 6;      // 4 waves
  const int lane = tid & 63;
  const int l15  = lane & 15;
  const int l4   = lane >> 4;
  const int wi   = wid >> 1;      // wave row over i (2)
  const int wj   = wid & 1;       // wave col over j (2)

  // LDS 48KB: 3 buffers x (A 8KB + B 8KB) -> 3 blocks/CU (144KB of 160KB)
  __shared__ char smem[49152];

  const int expK = *expKp;

  // read-side swizzle: slot = l4 ^ ((row>>1)&3); row = *+l15 -> ((l15>>1)&3)
  const int rsl = (l4 ^ ((l15 >> 1) & 3)) << 4;   // byte offset within row
  // stage-side: linear LDS dest; source col pre-swizzled (involution)
  const int scol = ((lane & 3) ^ ((lane >> 3) & 3)) * 8;   // bf16 column
  const int srow = lane >> 2;                               // row in 16-chunk

  // per stage per wave: 4 gload_lds (2 A-chunks + 2 B-chunks of 1KB)
  auto stage = [&](int buf, int i0s, int kks) {
    char* Ab_ = smem + buf * 16384;
    char* Bb_ = smem + buf * 16384 + 8192;
    #pragma unroll
    for (int q = 0; q < 2; ++q) {
      const int grow = wid * 32 + q * 16 + srow;
      const size_t gc = (size_t)kks * BK + scol;
      gload_lds16(Xr + (size_t)(i0s + grow) * DFEAT + gc,
                  Ab_ + wid * 2048 + q * 1024);
      gload_lds16(Xi + (size_t)(j0 + grow) * DFEAT + gc,
                  Bb_ + wid * 2048 + q * 1024);
    }
  };

  f32x4 accO[4][4];                       // p 64 x (this wave's j 64)
  #pragma unroll
  for (int a = 0; a < 4; ++a)
    #pragma unroll
    for (int n = 0; n < 4; ++n)
      accO[a][n] = (f32x4){0.f, 0.f, 0.f, 0.f};

  if (ntiles > 0) {
    // ---- prologue: depth-2 prefetch, NO drain ----
    stage(0, ibase + tile_begin * BI, 0);
    stage(1, ibase + tile_begin * BI, 1);

    for (int t = 0; t < ntiles; ++t) {
      const int i0c = ibase + (tile_begin + t) * BI;
      const int i0n = i0c + BI;

      f32x4 acc[4][4];
      #pragma unroll
      for (int m = 0; m < 4; ++m)
        #pragma unroll
        for (int n = 0; n < 4; ++n)
          acc[m][n] = (f32x4){0.f, 0.f, 0.f, 0.f};

      // ---- 12 K-steps; compute buf = ph%3, stage buf = (ph+2)%3 ----
      #pragma unroll
      for (int ph = 0; ph < KSTEPS; ++ph) {
        const int cb = ph % 3;
        const int sb = (ph + 2) % 3;
        if (ph <= 9) {
          stage(sb, i0c, ph + 2);
          asm volatile("s_waitcnt vmcnt(8)" ::: "memory");
        } else if (t + 1 < ntiles) {
          stage(sb, i0n, ph - 10);
          asm volatile("s_waitcnt vmcnt(8)" ::: "memory");
        } else if (ph == 10) {
          asm volatile("s_waitcnt vmcnt(4)" ::: "memory");
        } else {
          asm volatile("s_waitcnt vmcnt(0)" ::: "memory");
        }
        __builtin_amdgcn_s_barrier();     // all waves' step-ph loads landed

        char* Ab_ = smem + cb * 16384;
        char* Bb_ = smem + cb * 16384 + 8192;
        __builtin_amdgcn_s_setprio(1);
        {
          bf16x8 aF[4], bF[4];
          #pragma unroll
          for (int m = 0; m < 4; ++m) {
            const int rA = wi * 64 + m * 16 + l15;
            aF[m] = *reinterpret_cast<const bf16x8*>(Ab_ + rA * 64 + rsl);
          }
          #pragma unroll
          for (int n = 0; n < 4; ++n) {
            const int rB = wj * 64 + n * 16 + l15;
            bF[n] = *reinterpret_cast<const bf16x8*>(Bb_ + rB * 64 + rsl);
          }
          #pragma unroll
          for (int m = 0; m < 4; ++m)
            #pragma unroll
            for (int n = 0; n < 4; ++n)
              acc[m][n] = __builtin_amdgcn_mfma_f32_16x16x32_bf16(
                  aF[m], bF[n], acc[m][n], 0, 0, 0);
        }
        __builtin_amdgcn_s_setprio(0);
        asm volatile("s_waitcnt lgkmcnt(0)" ::: "memory");  // my reads done
        __builtin_amdgcn_s_barrier();     // buf cb free for overwrite
      }

      // ---- tail: square+pack, lane-local PV (aP drain once per tile) ----
      #pragma unroll
      for (int ks = 0; ks < 2; ++ks) {
        bf16x8 aP[4];
        #pragma unroll
        for (int a = 0; a < 4; ++a)
          aP[a] = *reinterpret_cast<const bf16x8*>(
              Abp + (size_t)(a * 16 + l15) * CAP + i0c + wi * 64 + ks * 32 + l4 * 8);
        #pragma unroll
        for (int n = 0; n < 4; ++n) {
          const f32x4 s0 = acc[2 * ks][n];
          const f32x4 s1 = acc[2 * ks + 1][n];
          u32x4 tw;
          tw[0] = (uint32_t)bfbits(pwr(s0[0], expK)) |
                  ((uint32_t)bfbits(pwr(s0[1], expK)) << 16);
          tw[1] = (uint32_t)bfbits(pwr(s0[2], expK)) |
                  ((uint32_t)bfbits(pwr(s0[3], expK)) << 16);
          tw[2] = (uint32_t)bfbits(pwr(s1[0], expK)) |
                  ((uint32_t)bfbits(pwr(s1[1], expK)) << 16);
          tw[3] = (uint32_t)bfbits(pwr(s1[2], expK)) |
                  ((uint32_t)bfbits(pwr(s1[3], expK)) << 16);
          const bf16x8 bP = __builtin_bit_cast(bf16x8, tw);
          __builtin_amdgcn_s_setprio(1);
          #pragma unroll
          for (int a = 0; a < 4; ++a)
            accO[a][n] = __builtin_amdgcn_mfma_f32_16x16x32_bf16(
                aP[a], bP, accO[a][n], 0, 0, 0);
          __builtin_amdgcn_s_setprio(0);
        }
      }
    }
  }

  // ---- cross-wi reduce via LDS (rb 32KB fits in 48KB smem) + bf16 store ----
  __syncthreads();
  float* rb = (float*)smem;        // [wj 2][p 64][j 64] floats
  if (wi == 1) {
    #pragma unroll
    for (int a = 0; a < 4; ++a)
      #pragma unroll
      for (int n = 0; n < 4; ++n)
        #pragma unroll
        for (int r = 0; r < 4; ++r)
          rb[wj * 4096 + (a * 16 + l4 * 4 + r) * 64 + n * 16 + l15] =
              accO[a][n][r];
  }
  __syncthreads();
  if (wi == 0) {
    unsigned short* po = partial + (size_t)split * NPROPS * CAP;
    #pragma unroll
    for (int a = 0; a < 4; ++a)
      #pragma unroll
      for (int n = 0; n < 4; ++n)
        #pragma unroll
        for (int r = 0; r < 4; ++r) {
          const int p = a * 16 + l4 * 4 + r;
          const int jl = wj * 64 + n * 16 + l15;
          po[(size_t)p * CAP + j0 + jl] =
              bfbits(accO[a][n][r] + rb[wj * 4096 + p * 64 + n * 16 + l15]);
        }
  }
}

extern "C" void kernel_launch(void* const* d_in, const int* in_sizes, int n_in,
                              void* d_out, int out_size, void* d_ws, size_t ws_size,
                              hipStream_t stream) {
  (void)in_sizes; (void)n_in; (void)out_size;
  const float* Alpha = (const float*)d_in[0];
  const float* X_ref = (const float*)d_in[1];
  const float* desc  = (const float*)d_in[2];
  const int*   Z_ref = (const int*)d_in[3];
  const int*   Z     = (const int*)d_in[4];
  const int*   expK  = (const int*)d_in[5];
  float* out = (float*)d_out;

  char* ws = (char*)d_ws;
  size_t off = 0;
  auto alloc = [&](size_t b) { void* p = ws + off; off = (off + b + 255) & ~255ULL; return p; };

  int* perm_i = (int*)alloc(CAP * 4);
  int* perm_j = (int*)alloc(CAP * 4);
  int* ioff   = (int*)alloc(8 * 4);
  int* joff   = (int*)alloc(8 * 4);
  __hip_bfloat16* Xr_g = (__hip_bfloat16*)alloc((size_t)CAP * DFEAT * 2);
  __hip_bfloat16* Xi_g = (__hip_bfloat16*)alloc((size_t)CAP * DFEAT * 2);
  __hip_bfloat16* Ab_g = (__hip_bfloat16*)alloc((size_t)NPROPS * CAP * 2);

  // nsplit=12 -> grid 816 (=8x102): 3 resident blocks/CU (48KB LDS, 128 VGPR)
  int nsplit = 12;
  while (nsplit > 4 && off + (size_t)nsplit * NPROPS * CAP * 2 > ws_size) nsplit -= 4;
  unsigned short* partial =
      (unsigned short*)alloc((size_t)nsplit * NPROPS * CAP * 2);

  partition2_kernel<<<dim3(2), 256, 0, stream>>>(
      Z_ref, Z, perm_i, perm_j, ioff, joff);

  gather_all<<<dim3(2 * XSEC + NPROPS * (CAP / 4) / 256), 256, 0, stream>>>(
      X_ref, desc, Alpha, perm_i, perm_j, Xr_g, Xi_g, Ab_g);

  const int grid = NSTRIP * nsplit;          // 816, divisible by 8
  fused_poly_kernel<<<dim3(grid), 256, 0, stream>>>(
      Xr_g, Xi_g, Ab_g, ioff, joff, expK, partial, nsplit, grid / 8);

  reduce_scatter<<<dim3(NPROPS * (CAP / 4) / 256), 256, 0, stream>>>(
      partial, perm_j, out, nsplit);
}

// Round 20
// 68.491 us; speedup vs baseline: 1.1296x; 1.0094x over previous
//
#include <hip/hip_runtime.h>
#include <hip/hip_bf16.h>
#include <stdint.h>

// y[p, j] = sum_i Alpha[p, i] * (X_ref[i] . X_in[j])^expK * [Z_ref[i] == Z[j]]
// Grouped formulation (4 element groups). Round-20 = round-17/19 config
// (best: 69.1us; fused kernel FROZEN at its measured optimum) with the two
// aux streaming kernels vectorized to 16B/lane (G13): gather_all X-sections
// store ushort8, reduce_scatter loads ushort8 per split. Fused kernel source
// byte-identical to r19.

typedef __attribute__((ext_vector_type(8))) short bf16x8;
typedef __attribute__((ext_vector_type(4))) float f32x4;
typedef __attribute__((ext_vector_type(4))) unsigned int u32x4;
typedef __attribute__((ext_vector_type(8))) unsigned short u16x8;

#define DFEAT  384
#define NREF   8192
#define NIN    8192
#define NPROPS 64
#define BJ 128
#define BI 128
#define BK 32
#define KSTEPS (DFEAT / BK)        // 12
#define CAP    8704                // 8192 + 4*128 (worst-case padded slots)
#define NSTRIP (CAP / BJ)          // 68

__device__ __forceinline__ void gload_lds16(const void* g, void* l) {
  __builtin_amdgcn_global_load_lds(
      (const __attribute__((address_space(1))) void*)g,
      (__attribute__((address_space(3))) void*)l,
      16, 0, 0);
}

__device__ __forceinline__ unsigned short bfbits(float f) {
  __hip_bfloat16 h = __float2bfloat16(f);
  return __builtin_bit_cast(unsigned short, h);
}

__device__ __forceinline__ float bf2f(unsigned short u) {
  return __builtin_bit_cast(float, (uint32_t)u << 16);
}

__device__ __forceinline__ float pwr(float s, int expK) {
  if (expK == 2) return s * s;
  float r = 1.0f;
  for (int e = 0; e < expK; ++e) r *= s;
  return r;
}

// ---- stable partition of both label arrays (2 blocks, one each) ----
__global__ __launch_bounds__(256) void partition2_kernel(
    const int* __restrict__ Za, const int* __restrict__ Zb,
    int* __restrict__ perma, int* __restrict__ permb,
    int* __restrict__ goffa, int* __restrict__ goffb) {
  const int* Zin = blockIdx.x ? Zb : Za;
  int* perm = blockIdx.x ? permb : perma;
  int* goff = blockIdx.x ? goffb : goffa;

  __shared__ int cnt[256][4];
  __shared__ int gstart[4];
  __shared__ int gtot[4];
  const int t = threadIdx.x;
  const int base = t * 32;           // 8192 / 256

  int c[4] = {0, 0, 0, 0};
  int zloc[32];
  #pragma unroll
  for (int e = 0; e < 32; ++e) {
    zloc[e] = (Zin[base + e] - 1) & 3;   // labels are 1..4
    ++c[zloc[e]];
  }
  #pragma unroll
  for (int b = 0; b < 4; ++b) cnt[t][b] = c[b];
  __syncthreads();

  const int w = t >> 6, l = t & 63;
  {
    int v0 = cnt[4 * l + 0][w], v1 = cnt[4 * l + 1][w];
    int v2 = cnt[4 * l + 2][w], v3 = cnt[4 * l + 3][w];
    int s = v0 + v1 + v2 + v3;
    int inc = s;
    #pragma unroll
    for (int d = 1; d < 64; d <<= 1) {
      int o = __shfl_up(inc, d, 64);
      if (l >= d) inc += o;
    }
    const int excl = inc - s;
    cnt[4 * l + 0][w] = excl;
    cnt[4 * l + 1][w] = excl + v0;
    cnt[4 * l + 2][w] = excl + v0 + v1;
    cnt[4 * l + 3][w] = excl + v0 + v1 + v2;
    if (l == 63) gtot[w] = inc;
  }
  __syncthreads();

  if (t == 0) {
    int off = 0;
    #pragma unroll
    for (int b = 0; b < 4; ++b) {
      gstart[b] = off; goff[b] = off;
      off += ((gtot[b] + 127) >> 7) << 7;   // pad to 128
    }
    goff[4] = off;
  }
  __syncthreads();

  for (int s = t; s < CAP; s += 256) perm[s] = -1;
  __syncthreads();

  int pos[4];
  #pragma unroll
  for (int b = 0; b < 4; ++b) pos[b] = gstart[b] + cnt[t][b];
  #pragma unroll
  for (int e = 0; e < 32; ++e) {
    const int z = zloc[e];
    perm[pos[z]++] = base + e;
  }
}

// ---- merged gather: Xr (perm_i), Xi (perm_j) at 16B/lane, Alpha permuted ----
#define XSEC8 (CAP * (DFEAT / 8) / 256)    // 1632 blocks per X section
__global__ void gather_all(const float* __restrict__ Xr_in,
                           const float* __restrict__ Xi_in,
                           const float* __restrict__ Al_in,
                           const int* __restrict__ perm_i,
                           const int* __restrict__ perm_j,
                           __hip_bfloat16* __restrict__ Xr_g,
                           __hip_bfloat16* __restrict__ Xi_g,
                           __hip_bfloat16* __restrict__ Ab_g) {
  const int b = blockIdx.x;
  if (b < 2 * XSEC8) {
    const bool isA = (b < XSEC8);
    const float* in = isA ? Xr_in : Xi_in;
    const int* perm = isA ? perm_i : perm_j;
    __hip_bfloat16* out = isA ? Xr_g : Xi_g;
    const int idx = (isA ? b : b - XSEC8) * 256 + threadIdx.x;
    const int per_row = DFEAT / 8;      // 48
    const int slot = idx / per_row;
    const int c8 = (idx % per_row) * 8;
    const int src = perm[slot];
    u16x8 o = (u16x8){0, 0, 0, 0, 0, 0, 0, 0};
    if (src >= 0) {
      const float4 v0 = *reinterpret_cast<const float4*>(in + (size_t)src * DFEAT + c8);
      const float4 v1 = *reinterpret_cast<const float4*>(in + (size_t)src * DFEAT + c8 + 4);
      o[0] = bfbits(v0.x); o[1] = bfbits(v0.y); o[2] = bfbits(v0.z); o[3] = bfbits(v0.w);
      o[4] = bfbits(v1.x); o[5] = bfbits(v1.y); o[6] = bfbits(v1.z); o[7] = bfbits(v1.w);
    }
    *reinterpret_cast<u16x8*>(out + (size_t)slot * DFEAT + c8) = o;
  } else {
    // Ab_g[p][32b + l4*8 + eh*4 + r] = Alpha[p][perm_i[32b + eh*16 + l4*4 + r]]
    const int t = (b - 2 * XSEC8) * 256 + threadIdx.x;   // NPROPS * CAP/4
    const int per_row = CAP / 4;
    const int p  = t / per_row;
    const int c4 = t % per_row;
    const int blk = c4 >> 3;
    const int g   = c4 & 7;
    const int l4g = g >> 1;
    const int eh  = g & 1;
    ushort4 o;
    unsigned short* op = &o.x;
    #pragma unroll
    for (int r = 0; r < 4; ++r) {
      const int slot = blk * 32 + eh * 16 + l4g * 4 + r;
      const int src = perm_i[slot];
      op[r] = (src >= 0) ? bfbits(Al_in[(size_t)p * NREF + src]) : (unsigned short)0;
    }
    *reinterpret_cast<ushort4*>(Ab_g + (size_t)p * CAP + blk * 32 + l4g * 8 + eh * 4) = o;
  }
}

// sum nsplit bf16 partials (16B/lane loads) and scatter to original columns
__global__ void reduce_scatter(const unsigned short* __restrict__ partial,
                               const int* __restrict__ permj,
                               float* __restrict__ out, int nsplit) {
  const int idx = blockIdx.x * blockDim.x + threadIdx.x;  // NPROPS * CAP / 8
  const int per_row = CAP / 8;        // 1088
  const int p = idx / per_row;
  const int s8 = (idx % per_row) * 8;
  float s[8] = {0.f, 0.f, 0.f, 0.f, 0.f, 0.f, 0.f, 0.f};
  for (int sp = 0; sp < nsplit; ++sp) {
    const u16x8 v = *reinterpret_cast<const u16x8*>(
        partial + (size_t)sp * NPROPS * CAP + (size_t)p * CAP + s8);
    #pragma unroll
    for (int e = 0; e < 8; ++e) s[e] += bf2f(v[e]);
  }
  const int4 d0 = *reinterpret_cast<const int4*>(permj + s8);
  const int4 d1 = *reinterpret_cast<const int4*>(permj + s8 + 4);
  float* po = out + (size_t)p * NIN;
  if (d0.x >= 0) po[d0.x] = s[0];
  if (d0.y >= 0) po[d0.y] = s[1];
  if (d0.z >= 0) po[d0.z] = s[2];
  if (d0.w >= 0) po[d0.w] = s[3];
  if (d1.x >= 0) po[d1.x] = s[4];
  if (d1.y >= 0) po[d1.y] = s[5];
  if (d1.z >= 0) po[d1.z] = s[6];
  if (d1.w >= 0) po[d1.w] = s[7];
}

__global__ __launch_bounds__(256, 2) void fused_poly_kernel(
    const __hip_bfloat16* __restrict__ Xr,   // [CAP][DFEAT] gathered ref rows
    const __hip_bfloat16* __restrict__ Xi,   // [CAP][DFEAT] gathered query rows
    const __hip_bfloat16* __restrict__ Abp,  // [NPROPS][CAP] gathered+permuted
    const int* __restrict__ ioff,            // [5] padded i-group offsets
    const int* __restrict__ joff,            // [5] padded j-group offsets
    const int* __restrict__ expKp,
    unsigned short* __restrict__ partial,    // [nsplit][NPROPS][CAP] bf16
    int nsplit, int chunk)                   // chunk = gridDim.x / 8
{
  // XCD-chunked bijective swizzle (round-6 proved FETCH 45->17MB)
  const int flat = blockIdx.x;
  const int newflat = (flat & 7) * chunk + (flat >> 3);
  const int strip = newflat / nsplit;
  const int split = newflat % nsplit;
  const int j0 = strip * BJ;
  if (j0 >= joff[4]) return;                 // dead strip

  int grp = 0;
  grp += (j0 >= joff[1]);
  grp += (j0 >= joff[2]);
  grp += (j0 >= joff[3]);
  const int ibase = ioff[grp];
  const int ntiles_g = (ioff[grp + 1] - ibase) / BI;
  const int tb = ntiles_g / nsplit;
  const int rem = ntiles_g % nsplit;
  const int ntiles = tb + (split < rem ? 1 : 0);
  const int tile_begin = split * tb + (split < rem ? split : rem);

  const int tid  = threadIdx.x;
  const int wid  = tid >> 6;      // 4 waves
  const int lane = tid & 63;
  const int l15  = lane & 15;
  const int l4   = lane >> 4;
  const int wi   = wid >> 1;      // wave row over i (2)
  const int wj   = wid & 1;       // wave col over j (2)

  // LDS 48KB: 3 buffers x (A 8KB + B 8KB) -> 3 blocks/CU (144KB of 160KB)
  __shared__ char smem[49152];

  const int expK = *expKp;

  // read-side swizzle: slot = l4 ^ ((row>>1)&3); row = *+l15 -> ((l15>>1)&3)
  const int rsl = (l4 ^ ((l15 >> 1) & 3)) << 4;   // byte offset within row
  // stage-side: linear LDS dest; source col pre-swizzled (involution)
  const int scol = ((lane & 3) ^ ((lane >> 3) & 3)) * 8;   // bf16 column
  const int srow = lane >> 2;                               // row in 16-chunk

  // per stage per wave: 4 gload_lds (2 A-chunks + 2 B-chunks of 1KB)
  auto stage = [&](int buf, int i0s, int kks) {
    char* Ab_ = smem + buf * 16384;
    char* Bb_ = smem + buf * 16384 + 8192;
    #pragma unroll
    for (int q = 0; q < 2; ++q) {
      const int grow = wid * 32 + q * 16 + srow;
      const size_t gc = (size_t)kks * BK + scol;
      gload_lds16(Xr + (size_t)(i0s + grow) * DFEAT + gc,
                  Ab_ + wid * 2048 + q * 1024);
      gload_lds16(Xi + (size_t)(j0 + grow) * DFEAT + gc,
                  Bb_ + wid * 2048 + q * 1024);
    }
  };

  f32x4 accO[4][4];                       // p 64 x (this wave's j 64)
  #pragma unroll
  for (int a = 0; a < 4; ++a)
    #pragma unroll
    for (int n = 0; n < 4; ++n)
      accO[a][n] = (f32x4){0.f, 0.f, 0.f, 0.f};

  if (ntiles > 0) {
    // ---- prologue: depth-2 prefetch, NO drain ----
    stage(0, ibase + tile_begin * BI, 0);
    stage(1, ibase + tile_begin * BI, 1);

    for (int t = 0; t < ntiles; ++t) {
      const int i0c = ibase + (tile_begin + t) * BI;
      const int i0n = i0c + BI;

      f32x4 acc[4][4];
      #pragma unroll
      for (int m = 0; m < 4; ++m)
        #pragma unroll
        for (int n = 0; n < 4; ++n)
          acc[m][n] = (f32x4){0.f, 0.f, 0.f, 0.f};

      // ---- 12 K-steps; compute buf = ph%3, stage buf = (ph+2)%3 ----
      #pragma unroll
      for (int ph = 0; ph < KSTEPS; ++ph) {
        const int cb = ph % 3;
        const int sb = (ph + 2) % 3;
        if (ph <= 9) {
          stage(sb, i0c, ph + 2);
          asm volatile("s_waitcnt vmcnt(8)" ::: "memory");
        } else if (t + 1 < ntiles) {
          stage(sb, i0n, ph - 10);
          asm volatile("s_waitcnt vmcnt(8)" ::: "memory");
        } else if (ph == 10) {
          asm volatile("s_waitcnt vmcnt(4)" ::: "memory");
        } else {
          asm volatile("s_waitcnt vmcnt(0)" ::: "memory");
        }
        __builtin_amdgcn_s_barrier();     // all waves' step-ph loads landed

        char* Ab_ = smem + cb * 16384;
        char* Bb_ = smem + cb * 16384 + 8192;
        __builtin_amdgcn_s_setprio(1);
        {
          bf16x8 aF[4], bF[4];
          #pragma unroll
          for (int m = 0; m < 4; ++m) {
            const int rA = wi * 64 + m * 16 + l15;
            aF[m] = *reinterpret_cast<const bf16x8*>(Ab_ + rA * 64 + rsl);
          }
          #pragma unroll
          for (int n = 0; n < 4; ++n) {
            const int rB = wj * 64 + n * 16 + l15;
            bF[n] = *reinterpret_cast<const bf16x8*>(Bb_ + rB * 64 + rsl);
          }
          #pragma unroll
          for (int m = 0; m < 4; ++m)
            #pragma unroll
            for (int n = 0; n < 4; ++n)
              acc[m][n] = __builtin_amdgcn_mfma_f32_16x16x32_bf16(
                  aF[m], bF[n], acc[m][n], 0, 0, 0);
        }
        __builtin_amdgcn_s_setprio(0);
        asm volatile("s_waitcnt lgkmcnt(0)" ::: "memory");  // my reads done
        __builtin_amdgcn_s_barrier();     // buf cb free for overwrite
      }

      // ---- tail: square+pack, lane-local PV (aP drain once per tile) ----
      #pragma unroll
      for (int ks = 0; ks < 2; ++ks) {
        bf16x8 aP[4];
        #pragma unroll
        for (int a = 0; a < 4; ++a)
          aP[a] = *reinterpret_cast<const bf16x8*>(
              Abp + (size_t)(a * 16 + l15) * CAP + i0c + wi * 64 + ks * 32 + l4 * 8);
        #pragma unroll
        for (int n = 0; n < 4; ++n) {
          const f32x4 s0 = acc[2 * ks][n];
          const f32x4 s1 = acc[2 * ks + 1][n];
          u32x4 tw;
          tw[0] = (uint32_t)bfbits(pwr(s0[0], expK)) |
                  ((uint32_t)bfbits(pwr(s0[1], expK)) << 16);
          tw[1] = (uint32_t)bfbits(pwr(s0[2], expK)) |
                  ((uint32_t)bfbits(pwr(s0[3], expK)) << 16);
          tw[2] = (uint32_t)bfbits(pwr(s1[0], expK)) |
                  ((uint32_t)bfbits(pwr(s1[1], expK)) << 16);
          tw[3] = (uint32_t)bfbits(pwr(s1[2], expK)) |
                  ((uint32_t)bfbits(pwr(s1[3], expK)) << 16);
          const bf16x8 bP = __builtin_bit_cast(bf16x8, tw);
          __builtin_amdgcn_s_setprio(1);
          #pragma unroll
          for (int a = 0; a < 4; ++a)
            accO[a][n] = __builtin_amdgcn_mfma_f32_16x16x32_bf16(
                aP[a], bP, accO[a][n], 0, 0, 0);
          __builtin_amdgcn_s_setprio(0);
        }
      }
    }
  }

  // ---- cross-wi reduce via LDS (rb 32KB fits in 48KB smem) + bf16 store ----
  __syncthreads();
  float* rb = (float*)smem;        // [wj 2][p 64][j 64] floats
  if (wi == 1) {
    #pragma unroll
    for (int a = 0; a < 4; ++a)
      #pragma unroll
      for (int n = 0; n < 4; ++n)
        #pragma unroll
        for (int r = 0; r < 4; ++r)
          rb[wj * 4096 + (a * 16 + l4 * 4 + r) * 64 + n * 16 + l15] =
              accO[a][n][r];
  }
  __syncthreads();
  if (wi == 0) {
    unsigned short* po = partial + (size_t)split * NPROPS * CAP;
    #pragma unroll
    for (int a = 0; a < 4; ++a)
      #pragma unroll
      for (int n = 0; n < 4; ++n)
        #pragma unroll
        for (int r = 0; r < 4; ++r) {
          const int p = a * 16 + l4 * 4 + r;
          const int jl = wj * 64 + n * 16 + l15;
          po[(size_t)p * CAP + j0 + jl] =
              bfbits(accO[a][n][r] + rb[wj * 4096 + p * 64 + n * 16 + l15]);
        }
  }
}

extern "C" void kernel_launch(void* const* d_in, const int* in_sizes, int n_in,
                              void* d_out, int out_size, void* d_ws, size_t ws_size,
                              hipStream_t stream) {
  (void)in_sizes; (void)n_in; (void)out_size;
  const float* Alpha = (const float*)d_in[0];
  const float* X_ref = (const float*)d_in[1];
  const float* desc  = (const float*)d_in[2];
  const int*   Z_ref = (const int*)d_in[3];
  const int*   Z     = (const int*)d_in[4];
  const int*   expK  = (const int*)d_in[5];
  float* out = (float*)d_out;

  char* ws = (char*)d_ws;
  size_t off = 0;
  auto alloc = [&](size_t b) { void* p = ws + off; off = (off + b + 255) & ~255ULL; return p; };

  int* perm_i = (int*)alloc(CAP * 4);
  int* perm_j = (int*)alloc(CAP * 4);
  int* ioff   = (int*)alloc(8 * 4);
  int* joff   = (int*)alloc(8 * 4);
  __hip_bfloat16* Xr_g = (__hip_bfloat16*)alloc((size_t)CAP * DFEAT * 2);
  __hip_bfloat16* Xi_g = (__hip_bfloat16*)alloc((size_t)CAP * DFEAT * 2);
  __hip_bfloat16* Ab_g = (__hip_bfloat16*)alloc((size_t)NPROPS * CAP * 2);

  // nsplit=12 -> grid 816 (=8x102): 3 resident blocks/CU (48KB LDS, 128 VGPR)
  int nsplit = 12;
  while (nsplit > 4 && off + (size_t)nsplit * NPROPS * CAP * 2 > ws_size) nsplit -= 4;
  unsigned short* partial =
      (unsigned short*)alloc((size_t)nsplit * NPROPS * CAP * 2);

  partition2_kernel<<<dim3(2), 256, 0, stream>>>(
      Z_ref, Z, perm_i, perm_j, ioff, joff);

  gather_all<<<dim3(2 * XSEC8 + NPROPS * (CAP / 4) / 256), 256, 0, stream>>>(
      X_ref, desc, Alpha, perm_i, perm_j, Xr_g, Xi_g, Ab_g);

  const int grid = NSTRIP * nsplit;          // 816, divisible by 8
  fused_poly_kernel<<<dim3(grid), 256, 0, stream>>>(
      Xr_g, Xi_g, Ab_g, ioff, joff, expK, partial, nsplit, grid / 8);

  reduce_scatter<<<dim3(NPROPS * (CAP / 8) / 256), 256, 0, stream>>>(
      partial, perm_j, out, nsplit);
}